// Round 8
// baseline (621.969 us; speedup 1.0000x reference)
//
#include <hip/hip_runtime.h>
#include <math.h>

typedef __bf16 bf16_t;
typedef bf16_t bf16x4 __attribute__((ext_vector_type(4)));
typedef bf16_t bf16x8 __attribute__((ext_vector_type(8)));
typedef float  f32x2  __attribute__((ext_vector_type(2)));
typedef float  f32x16 __attribute__((ext_vector_type(16)));

#define HH 1024
#define CC 8
#define DD 64
#define FF 32
#define WW 7
#define HP 1018
#define HPAD 1024
#define NF 128
#define QOUT (NF*HP*DD)
#define QWS ((size_t)NF*HPAD*DD)
#define SCEXP (1.442695041f/1018.f)     // log2(e)/1018, pre-applied to q1

#if __has_builtin(__builtin_amdgcn_exp2f)
#define EXP2(x) __builtin_amdgcn_exp2f(x)
#else
#define EXP2(x) __expf((x) * 0.6931471805599453f)
#endif

// Vt: row stride 64 bf16, XOR-swizzled 8-element chunks (validated R4-R7):
__device__ __forceinline__ int vaddr(int row, int col) {
    return row*64 + ((((col>>3) ^ (row&7) ^ ((row>>2)&7)))<<3) + (col&7);
}

// ---------------- W prep: Wt[f][c][d][j] -> Wp[f][cp][j][d][e] (c-paired float2) ----
__global__ __launch_bounds__(256) void wprep_kernel(
    const float* __restrict__ Wt, float* __restrict__ Wp)
{
    const int idx = blockIdx.x * 256 + threadIdx.x;
    if (idx < FF*CC*DD*WW) {
        const int e = idx & 1;
        int t = idx >> 1;
        const int d = t & 63; t >>= 6;
        const int j = t % WW; t /= WW;
        const int cp = t & 3;
        const int f = t >> 2;
        Wp[idx] = Wt[((f*CC + 2*cp + e)*DD + d)*WW + j];
    }
}

// ---------------- x transpose: x[n][row][c][d] fp32 -> xt[z][n][row][d][c] bf16 ----
__global__ __launch_bounds__(256) void xprep_kernel(
    const float* __restrict__ x1, const float* __restrict__ x2,
    bf16_t* __restrict__ xt)
{
    __shared__ float ls[8][CC][DD+1];
    const float* x = blockIdx.z ? x2 : x1;
    bf16_t* o = xt + (size_t)blockIdx.z * (4*HH*512);
    const int n = blockIdx.y;
    const int r0 = blockIdx.x * 8;
    const int tid = threadIdx.x;

#pragma unroll
    for (int it = 0; it < 4; ++it) {
        const int i = it*256 + tid;
        const int r = i >> 7;
        const int idx = i & 127;
        const int c = idx >> 4;
        const int d0 = (idx & 15) * 4;
        float4 v = *(const float4*)&x[((size_t)(n*HH + r0 + r)*CC + c)*DD + d0];
        ls[r][c][d0+0] = v.x; ls[r][c][d0+1] = v.y;
        ls[r][c][d0+2] = v.z; ls[r][c][d0+3] = v.w;
    }
    __syncthreads();
    const int d = tid & 63;
    for (int r = (tid >> 6); r < 8; r += 4) {
        bf16_t tmp[8];
#pragma unroll
        for (int c = 0; c < CC; ++c) tmp[c] = (bf16_t)ls[r][c][d];
        *(bf16x8*)&o[((size_t)(n*HH + r0 + r)*DD + d)*CC] = *(bf16x8*)tmp;
    }
}

// ---------------- projection (grouped conv), pk_fma over c-pairs ----------------
__global__ __launch_bounds__(256, 4) void conv_kernel(
    const bf16_t* __restrict__ xt, const float* __restrict__ Wp,
    bf16_t* __restrict__ q1, bf16_t* __restrict__ q2)
{
    __shared__ __align__(16) bf16_t xs[22*64*8];   // [rr][d][c], linear staging
    const int z = blockIdx.z;
    const bf16_t* xb = xt + (size_t)z * (4*HH*512);
    bf16_t* q = z ? q2 : q1;
    const float qscale = z ? 1.0f : SCEXP;
    const int n = blockIdx.y;
    const int hb = blockIdx.x * 16;
    const int tid = threadIdx.x;

    for (int i = tid; i < 22*64; i += 256) {
        const int row = hb + (i >> 6);
        const int dd = i & 63;
        bf16x8 v = {};
        if (row < HH) v = *(const bf16x8*)&xb[((size_t)(n*HH + row)*DD + dd)*CC];
        *(bf16x8*)&xs[(size_t)i*8] = v;
    }
    __syncthreads();

    const int d = tid & 63;
    const int fq = tid >> 6;
#pragma unroll 1
    for (int fi = 0; fi < 8; ++fi) {               // KEEP ROLLED: unrolling spills
        const int f = fq*8 + fi;
        f32x2 w2[4][WW];
#pragma unroll
        for (int cp = 0; cp < 4; ++cp)
#pragma unroll
            for (int j = 0; j < WW; ++j)
                w2[cp][j] = *(const f32x2*)&Wp[((((f*4 + cp)*WW + j)*DD) + d)*2];
        f32x2 acc2[16];
#pragma unroll
        for (int i = 0; i < 16; ++i) acc2[i] = (f32x2){0.f, 0.f};
#pragma unroll
        for (int rr = 0; rr < 22; ++rr) {
            bf16x8 xv8 = *(const bf16x8*)&xs[(rr*64 + d)*8];
            f32x2 xv2[4];
#pragma unroll
            for (int cp = 0; cp < 4; ++cp) {
                xv2[cp][0] = (float)xv8[2*cp+0];
                xv2[cp][1] = (float)xv8[2*cp+1];
            }
#pragma unroll
            for (int j = 0; j < WW; ++j) {
                const int i = rr - j;
                if (i >= 0 && i < 16) {
#pragma unroll
                    for (int cp = 0; cp < 4; ++cp)
                        acc2[i] += xv2[cp] * w2[cp][j];   // -> v_pk_fma_f32
                }
            }
        }
#pragma unroll
        for (int i = 0; i < 16; ++i) {
            const int h = hb + i;
            const float v = (h < HP) ? (acc2[i][0] + acc2[i][1]) * qscale : 0.f;
            q[((size_t)(n*FF + f)*HPAD + h)*DD + d] = (bf16_t)v;
        }
    }
}

__device__ __forceinline__ float fast_tanh(float x) {
    const float t = __expf(2.f * x);
    return (t - 1.f) / (t + 1.f);
}

// ---------------- fused flash pass (MFMA), 32 h-rows/wave ----------------
// Sᵀ = Q2·Q1ᵀ : C/D col=lane&31 -> h; row=(reg&3)+8*(reg>>2)+4*(lane>>5) -> g.
// A-frags from global (L1/L2-hot, prefetched); Vt swizzled in LDS (8 KB only).
// l row-sums on the matrix pipe via B=ones MFMA (reg-index-matched with O).
template<int MODE>
__global__ __launch_bounds__(256, 3) void flash(
    const bf16_t* __restrict__ q1, const bf16_t* __restrict__ q2,
    const bf16_t* __restrict__ vsrc, bf16_t* __restrict__ p1out,
    float* __restrict__ out)
{
    __shared__ __align__(16) bf16_t Vt[64*64];

    const int head = blockIdx.y;
    const int n = head >> 5, f = head & 31;
    const int tid = threadIdx.x;
    const int w = tid >> 6;
    const int lane = tid & 63;
    const int lid = lane & 31;
    const int half = lane >> 5;
    const int hb = blockIdx.x * 128 + w * 32;      // 32 rows per wave

    const size_t qoff = (size_t)head * HPAD * DD;
    const int vswz = (lid & 7) ^ (lid >> 2);

    const int gq = tid >> 4;
    const int dq = tid & 15;
    const int cgb = 4*((gq>>1)&1) + 8*(gq&1) + 16*(gq>>2);

    const bf16_t* vptr = (MODE == 1) ? vsrc : q2;

    // Q1 B-fragments (pre-scaled by SCEXP in conv), persistent
    bf16x8 bq1[4];
#pragma unroll
    for (int kt = 0; kt < 4; ++kt)
        bq1[kt] = *(const bf16x8*)&q1[qoff + (size_t)(hb + lid)*DD + 16*kt + 8*half];

    bf16x8 onesb;
#pragma unroll
    for (int j = 0; j < 8; ++j) onesb[j] = (bf16_t)1.0f;

    // A-fragments for tile 0 (from global)
    bf16x8 aq[2][4];
#pragma unroll
    for (int mt = 0; mt < 2; ++mt)
#pragma unroll
        for (int kt = 0; kt < 4; ++kt)
            aq[mt][kt] = *(const bf16x8*)&q2[qoff + (size_t)(32*mt + lid)*DD + 16*kt + 8*half];

    // V staging regs for tile 0
    bf16x4 rV[4];
#pragma unroll
    for (int i = 0; i < 4; ++i)
        rV[i] = *(const bf16x4*)&vptr[qoff + (size_t)(4*gq + i)*DD + 4*dq];

    f32x16 O[2] = {};
    f32x16 lO = {};

    for (int g0 = 0; g0 < HPAD; g0 += 64) {
        __syncthreads();
#pragma unroll
        for (int j = 0; j < 4; ++j) {
            bf16x4 c = { rV[0][j], rV[1][j], rV[2][j], rV[3][j] };
            *(bf16x4*)&Vt[vaddr(4*dq + j, cgb)] = c;
        }
        __syncthreads();

        if (g0 + 64 < HPAD) {
#pragma unroll
            for (int i = 0; i < 4; ++i)
                rV[i] = *(const bf16x4*)&vptr[qoff + (size_t)(g0 + 64 + 4*gq + i)*DD + 4*dq];
        }

        const bool tail = (g0 + 64 > HP);

#pragma unroll
        for (int mt = 0; mt < 2; ++mt) {
            // ---- S-phase ----
            f32x16 C = {};
#pragma unroll
            for (int kt = 0; kt < 4; ++kt)
                C = __builtin_amdgcn_mfma_f32_32x32x16_bf16(aq[mt][kt], bq1[kt], C, 0,0,0);
            // reload this mt's A-frags for the NEXT tile
            if (g0 + 64 < HPAD) {
#pragma unroll
                for (int kt = 0; kt < 4; ++kt)
                    aq[mt][kt] = *(const bf16x8*)&q2[qoff + (size_t)(g0 + 64 + 32*mt + lid)*DD + 16*kt + 8*half];
            }
            // ---- exp (q1 pre-scaled) + pack PV A-frags ----
            bf16x8 af[2];
#pragma unroll
            for (int s = 0; s < 16; ++s) {
                float e = EXP2((float)C[s]);
                if (tail) {
                    const int gg = g0 + 32*mt + (s&3) + 8*(s>>2) + 4*half;
                    if (gg >= HP) e = 0.f;
                }
                af[s>>3][s&7] = (bf16_t)e;
            }
            // ---- l row-sums on the matrix pipe ----
#pragma unroll
            for (int u = 0; u < 2; ++u)
                lO = __builtin_amdgcn_mfma_f32_32x32x16_bf16(af[u], onesb, lO, 0,0,0);
            // ---- PV ----
#pragma unroll
            for (int u = 0; u < 2; ++u) {
#pragma unroll
                for (int dt = 0; dt < 2; ++dt) {
                    const int chunk = (4*mt + 2*u + half) ^ vswz;
                    bf16x8 b = *(const bf16x8*)&Vt[(32*dt + lid)*64 + chunk*8];
                    O[dt] = __builtin_amdgcn_mfma_f32_32x32x16_bf16(af[u], b, O[dt], 0,0,0);
                }
            }
        }
    }

    // ---- epilogue ----
#pragma unroll
    for (int s = 0; s < 16; ++s) {
        const int R = (s&3) + 8*(s>>2) + 4*half;
        const int hg = hb + R;
        const float linv = 1.f / lO[s];
#pragma unroll
        for (int dt = 0; dt < 2; ++dt) {
            const int d = 32*dt + lid;
            const float val = O[dt][s] * linv;
            if (hg < HP)
                out[(((size_t)n*HP + hg)*FF + f)*DD + d] = fast_tanh(val);
            if (MODE == 0)
                p1out[qoff + (size_t)hg*DD + d] = (bf16_t)(hg < HP ? val : 0.f);
        }
    }
}

extern "C" void kernel_launch(void* const* d_in, const int* in_sizes, int n_in,
                              void* d_out, int out_size, void* d_ws, size_t ws_size,
                              hipStream_t stream)
{
    const float* prot1 = (const float*)d_in[0];
    const float* prot2 = (const float*)d_in[1];
    const float* Wt    = (const float*)d_in[2];
    float* out = (float*)d_out;

    bf16_t* q1b = (bf16_t*)d_ws;
    bf16_t* q2b = q1b + QWS;
    bf16_t* p1b = q2b + QWS;
    float*  Wp  = (float*)(p1b + QWS);             // FF*CC*DD*WW floats (c-paired)
    bf16_t* xtb = (bf16_t*)(Wp + FF*CC*DD*WW);     // 8 MB

    wprep_kernel<<<dim3(448), 256, 0, stream>>>(Wt, Wp);
    xprep_kernel<<<dim3(HH/8, 4, 2), 256, 0, stream>>>(prot1, prot2, xtb);
    conv_kernel<<<dim3(64, 4, 2), 256, 0, stream>>>(xtb, Wp, q1b, q2b);
    flash<0><<<dim3(8, NF), 256, 0, stream>>>(q1b, q2b, q2b, p1b, out);
    flash<1><<<dim3(8, NF), 256, 0, stream>>>(q1b, q2b, p1b, p1b, out + QOUT);
}